// Round 3
// baseline (1242.060 us; speedup 1.0000x reference)
//
#include <hip/hip_runtime.h>
#include <hip/hip_bf16.h>

typedef float f32x4 __attribute__((ext_vector_type(4)));
typedef short s16x8 __attribute__((ext_vector_type(8)));
typedef unsigned int u32;
typedef unsigned short ushort_t;

#define NF 1024
#define OF 1024
#define KV 9216          // 1024 base + 1024*8 spline

static __device__ __forceinline__ float silu_f(float x) {
    return x / (1.f + __expf(-x));
}

static __device__ __forceinline__ unsigned short f2bf(float f) {
    unsigned int u = __float_as_uint(f);
    return (unsigned short)((u + 0x7FFFu + ((u >> 16) & 1u)) >> 16);
}

// Cubic B-spline over knots t_j = -2.2 + 0.4*j (j=0..11): 4 taps at slots p..p+3.
static __device__ __forceinline__ void basis_taps(float x, float w[4], int &p) {
    float t  = __fmaf_rn(x, 2.5f, 5.5f);
    float jf = floorf(t);
    float u  = t - jf;
    int   j  = (int)jf;
    float um  = 1.f - u;
    float um2 = um * um;
    float u2  = u * u;
    float w0 = um2 * um * (1.f / 6.f);
    float w3 = u2 * u * (1.f / 6.f);
    float w1 = __fmaf_rn(0.5f * u, u2, -u2) + (2.f / 3.f);
    float w2 = 1.f - w0 - w1 - w3;
    w[0] = w0; w[1] = w1; w[2] = w2; w[3] = w3;
    p = (j >= 0 && j <= 10) ? (j - 3) : -10000;
}

// 8 bf16 basis slots for one x, packed in a uint4 (taps shifted into place).
static __device__ __forceinline__ uint4 spline_pack8(float x) {
    float w[4]; int p;
    basis_taps(x, w, p);
    unsigned long long taps =
          (unsigned long long)f2bf(w[0])
        | ((unsigned long long)f2bf(w[1]) << 16)
        | ((unsigned long long)f2bf(w[2]) << 32)
        | ((unsigned long long)f2bf(w[3]) << 48);
    int bsh = p << 4;
    unsigned long long lo = 0ull, hi = 0ull;
    if (bsh >= 0) {
        if (bsh < 64)       { lo = taps << bsh; hi = bsh ? (taps >> (64 - bsh)) : 0ull; }
        else if (bsh < 128) { hi = taps << (bsh - 64); }
    } else if (bsh > -64)   { lo = taps >> (-bsh); }
    uint4 v;
    v.x = (u32)lo; v.y = (u32)(lo >> 32); v.z = (u32)hi; v.w = (u32)(hi >> 32);
    return v;
}

static __device__ __forceinline__ u32 pack2(float a, float b) {
    return (u32)f2bf(a) | ((u32)f2bf(b) << 16);
}

// ============================ FAST PATH ====================================

// A_aug (4096,9216) bf16: [0,1024) = silu(x); [1024+f*8+s] = basis_s(x_f).
__global__ __launch_bounds__(256)
void prep_a(const float* __restrict__ X, ushort_t* __restrict__ Aa) {
    const int gid = blockIdx.x * 256 + threadIdx.x;   // 4718592 threads
    if (gid < 524288) {                               // base region, 8 elems each
        const int m = gid >> 7, c8 = (gid & 127) << 3;
        const float4* xp = (const float4*)(X + (((size_t)m) << 10) + c8);
        float4 a = xp[0], b = xp[1];
        uint4 v;
        v.x = pack2(silu_f(a.x), silu_f(a.y));
        v.y = pack2(silu_f(a.z), silu_f(a.w));
        v.z = pack2(silu_f(b.x), silu_f(b.y));
        v.w = pack2(silu_f(b.z), silu_f(b.w));
        *(uint4*)(Aa + (size_t)m * KV + c8) = v;
    } else {                                          // spline region, 1 feature each
        const int sid = gid - 524288;
        const int m = sid >> 10, f = sid & 1023;
        float x = X[(((size_t)m) << 10) + f];
        *(uint4*)(Aa + (size_t)m * KV + 1024 + (f << 3)) = spline_pack8(x);
    }
}

// B_aug (1024,9216) bf16: [0,1024)=Wb; [1024+f*8+s]=Ws[o][f][s]*Wc[o][f].
__global__ __launch_bounds__(256)
void prep_b(const float* __restrict__ Wb, const float* __restrict__ Ws,
            const float* __restrict__ Wc, ushort_t* __restrict__ Ba) {
    const int gid = blockIdx.x * 256 + threadIdx.x;   // 1179648 threads
    const int o = gid / 1152;
    const int r = gid - o * 1152;
    uint4 v;
    size_t dst;
    if (r < 128) {
        const int k8 = r << 3;
        const float4* wp = (const float4*)(Wb + (((size_t)o) << 10) + k8);
        float4 a = wp[0], b = wp[1];
        v.x = pack2(a.x, a.y); v.y = pack2(a.z, a.w);
        v.z = pack2(b.x, b.y); v.w = pack2(b.z, b.w);
        dst = (size_t)o * KV + k8;
    } else {
        const int f = r - 128;
        const float sc = Wc[(((size_t)o) << 10) + f];
        const float4* sp = (const float4*)(Ws + ((((size_t)o) << 10) + f) * 8);
        float4 a = sp[0], b = sp[1];
        v.x = pack2(a.x * sc, a.y * sc); v.y = pack2(a.z * sc, a.w * sc);
        v.z = pack2(b.x * sc, b.y * sc); v.w = pack2(b.z * sc, b.w * sc);
        dst = (size_t)o * KV + 1024 + (f << 3);
    }
    *(uint4*)(Ba + dst) = v;
}

// Pure bf16 NT-GEMM: 128x64 tile, BK=64, reg-staged LDS with XOR swizzle
// (byte ^= (row&7)<<4 — R1-proven, 0 bank conflicts), next-chunk prefetch.
template<int ACT>
__global__ __launch_bounds__(256)
void kan_gemm3(const ushort_t* __restrict__ A,   // (4096, KV)
               const ushort_t* __restrict__ B,   // (1024, KV)
               float* __restrict__ Out)          // (4096, 1024)
{
    __shared__ alignas(16) char As[128 * 128];   // 128 rows x 64 bf16 (swizzled)
    __shared__ alignas(16) char Bs[64 * 128];    // 64 rows x 64 bf16 (swizzled)

    const int t = threadIdx.x, lane = t & 63, wid = t >> 6;
    const int wr = wid >> 1, wcn = wid & 1;      // 2x2 wave grid, 64x32 per wave
    // bijective XCD swizzle (512 % 8 == 0)
    const int bb  = blockIdx.x;
    const int lb  = (bb & 7) * 64 + (bb >> 3);
    const int row0 = (lb >> 4) << 7;             // 32 row-blocks
    const int col0 = (lb & 15) << 6;             // 16 col-blocks
    const int l8 = lane >> 3, l7 = lane & 7;

    f32x4 acc[4][2];
    #pragma unroll
    for (int i = 0; i < 4; ++i)
        #pragma unroll
        for (int j = 0; j < 2; ++j)
            acc[i][j] = (f32x4){0.f, 0.f, 0.f, 0.f};

    // per-thread staging map: A rows slotA*8+l8 (slotA=wid*4+i), B rows slotB*8+l8
    uint4 ra[4], rb[2];
    #pragma unroll
    for (int i = 0; i < 4; ++i) {
        const int row = (((wid << 2) + i) << 3) + l8;
        ra[i] = *(const uint4*)(A + (size_t)(row0 + row) * KV + (l7 << 3));
    }
    #pragma unroll
    for (int i = 0; i < 2; ++i) {
        const int row = (((i << 2) + wid) << 3) + l8;
        rb[i] = *(const uint4*)(B + (size_t)(col0 + row) * KV + (l7 << 3));
    }

    for (int ch = 0; ch < 144; ++ch) {
        __syncthreads();                 // prior chunk's ds_reads all done
        #pragma unroll
        for (int i = 0; i < 4; ++i) {
            const int row = (((wid << 2) + i) << 3) + l8;
            *(uint4*)(As + row * 128 + ((l7 << 4) ^ ((row & 7) << 4))) = ra[i];
        }
        #pragma unroll
        for (int i = 0; i < 2; ++i) {
            const int row = (((i << 2) + wid) << 3) + l8;
            *(uint4*)(Bs + row * 128 + ((l7 << 4) ^ ((row & 7) << 4))) = rb[i];
        }
        if (ch < 143) {                  // prefetch next chunk into regs
            const int k0 = (ch + 1) << 6;
            #pragma unroll
            for (int i = 0; i < 4; ++i) {
                const int row = (((wid << 2) + i) << 3) + l8;
                ra[i] = *(const uint4*)(A + (size_t)(row0 + row) * KV + k0 + (l7 << 3));
            }
            #pragma unroll
            for (int i = 0; i < 2; ++i) {
                const int row = (((i << 2) + wid) << 3) + l8;
                rb[i] = *(const uint4*)(B + (size_t)(col0 + row) * KV + k0 + (l7 << 3));
            }
        }
        __syncthreads();                 // ds_writes visible to all

        #pragma unroll
        for (int ks = 0; ks < 2; ++ks) {
            const int kcb = ((ks << 5) + ((lane >> 4) << 3)) << 1;   // byte offset
            s16x8 af[4], bf2[2];
            #pragma unroll
            for (int i = 0; i < 4; ++i) {
                const int r = (wr << 6) + (i << 4) + (lane & 15);
                af[i] = *(const s16x8*)(As + r * 128 + (kcb ^ ((r & 7) << 4)));
            }
            #pragma unroll
            for (int j = 0; j < 2; ++j) {
                const int r = (wcn << 5) + (j << 4) + (lane & 15);
                bf2[j] = *(const s16x8*)(Bs + r * 128 + (kcb ^ ((r & 7) << 4)));
            }
            #pragma unroll
            for (int i = 0; i < 4; ++i)
                #pragma unroll
                for (int j = 0; j < 2; ++j)
                    acc[i][j] = __builtin_amdgcn_mfma_f32_16x16x32_bf16(af[i], bf2[j], acc[i][j], 0, 0, 0);
        }
    }

    const int crow = (lane >> 4) << 2, ccol = lane & 15;
    #pragma unroll
    for (int i = 0; i < 4; ++i)
        #pragma unroll
        for (int j = 0; j < 2; ++j)
            #pragma unroll
            for (int q = 0; q < 4; ++q) {
                int r = row0 + (wr << 6) + (i << 4) + crow + q;
                int c = col0 + (wcn << 5) + (j << 4) + ccol;
                float v = acc[i][j][q];
                if (ACT) v = (v >= 0.f) ? v : 0.1f * v;
                Out[(size_t)r * OF + c] = v;
            }
}

// Fused layers 2+3, 4 wave-groups over H + LDS combine: grid 64*16 blocks.
__global__ __launch_bounds__(256)
void kan_mid2(const float* __restrict__ xemb,
              const float* __restrict__ w2b, const float* __restrict__ w2s, const float* __restrict__ w2c,
              const float* __restrict__ w3b, const float* __restrict__ w3s, const float* __restrict__ w3c,
              float* __restrict__ xcomb, float* __restrict__ xde)
{
    __shared__ float s_w2sc[64][8];
    __shared__ float s_w2b[64];
    __shared__ float s_w3sc[64][8];
    __shared__ float s_w3b[64];
    __shared__ float partial[4][64];
    __shared__ float s_acc[64];
    const int t = threadIdx.x;
    if (t < 64) { s_w2b[t] = w2b[t]; s_w3b[t] = w3b[t]; }
    for (int i = t; i < 512; i += 256) {
        s_w2sc[i >> 3][i & 7] = w2s[i] * w2c[i >> 3];
        s_w3sc[i >> 3][i & 7] = w3s[i] * w3c[i >> 3];
    }
    __syncthreads();

    const int b  = blockIdx.x >> 4;
    const int d0 = (blockIdx.x & 15) << 6;
    const int hg = t >> 6, dd = t & 63;

    float sum = 0.f;
    #pragma unroll 4
    for (int hh = 0; hh < 16; ++hh) {
        const int h = (hg << 4) + hh;
        float e = xemb[(((size_t)(b << 6) + h) << 10) + d0 + dd];
        float w[4]; int p;
        basis_taps(e, w, p);
        float sp = 0.f;
        #pragma unroll
        for (int m2 = 0; m2 < 4; ++m2) {
            int idx = p + m2;
            if ((unsigned)idx < 8u) sp += w[m2] * s_w2sc[h][idx];
        }
        sum += silu_f(e) * s_w2b[h] + sp;
    }
    partial[hg][dd] = sum;
    __syncthreads();
    if (hg == 0) {
        float a = partial[0][dd] + partial[1][dd] + partial[2][dd] + partial[3][dd];
        s_acc[dd] = a;
        xcomb[(b << 10) + d0 + dd] = a;
    }
    __syncthreads();

    const float accv = s_acc[dd];
    float w[4]; int p;
    basis_taps(accv, w, p);
    const float sl = silu_f(accv);
    #pragma unroll 4
    for (int hh = 0; hh < 16; ++hh) {
        const int h = (hg << 4) + hh;
        float sp = 0.f;
        #pragma unroll
        for (int m2 = 0; m2 < 4; ++m2) {
            int idx = p + m2;
            if ((unsigned)idx < 8u) sp += w[m2] * s_w3sc[h][idx];
        }
        float v = sl * s_w3b[h] + sp;
        v = (v >= 0.f) ? v : 0.1f * v;
        xde[(((size_t)(b << 6) + h) << 10) + d0 + dd] = v;
    }
}

// ========================= FALLBACK PATH (R1, passing) =====================

static __device__ __forceinline__ void st_bf16x4(char* lds, int r, int c4,
                                                 float a, float b, float c, float d) {
    unsigned int lo = (unsigned int)f2bf(a) | ((unsigned int)f2bf(b) << 16);
    unsigned int hi = (unsigned int)f2bf(c) | ((unsigned int)f2bf(d) << 16);
    int byte = r * 128 + (((c4 << 1) ^ ((r & 7) << 4)));
    uint2 v; v.x = lo; v.y = hi;
    *reinterpret_cast<uint2*>(lds + byte) = v;
}

static __device__ __forceinline__ s16x8 ld_frag(const char* lds, int r, int c) {
    int byte = r * 128 + (((c << 1) ^ ((r & 7) << 4)));
    return *reinterpret_cast<const s16x8*>(lds + byte);
}

template<int ACT>
__global__ __launch_bounds__(256)
void kan_gemm(const float* __restrict__ X, const float* __restrict__ Wb,
              const float* __restrict__ Ws, const float* __restrict__ Wc,
              float* __restrict__ Out)
{
    __shared__ alignas(16) char As[128 * 128];
    __shared__ alignas(16) char Bs[128 * 128];
    const int t = threadIdx.x, lane = t & 63, wid = t >> 6;
    const int wr = wid >> 1, wcn = wid & 1;
    const int row0 = blockIdx.x * 128, col0 = blockIdx.y * 128;
    f32x4 acc[4][4];
    #pragma unroll
    for (int i = 0; i < 4; ++i)
        #pragma unroll
        for (int j = 0; j < 4; ++j) acc[i][j] = (f32x4){0.f, 0.f, 0.f, 0.f};
    const int rs = t >> 4, c4 = (t & 15) << 2;
    for (int ch = 0; ch < 144; ++ch) {
        __syncthreads();
        if (ch < 16) {
            const int i0 = ch << 6;
            #pragma unroll
            for (int ps = 0; ps < 8; ++ps) {
                const int rr = (ps << 4) + rs;
                float4 xv = *(const float4*)(X + (size_t)(row0 + rr) * NF + i0 + c4);
                st_bf16x4(As, rr, c4, silu_f(xv.x), silu_f(xv.y), silu_f(xv.z), silu_f(xv.w));
                float4 wv = *(const float4*)(Wb + (size_t)(col0 + rr) * NF + i0 + c4);
                st_bf16x4(Bs, rr, c4, wv.x, wv.y, wv.z, wv.w);
            }
        } else {
            const int f0 = (ch - 16) << 3;
            #pragma unroll
            for (int ps = 0; ps < 8; ++ps) {
                const int rr = (ps << 4) + rs;
                float4 sv = *(const float4*)(Ws + (size_t)(col0 + rr) * (NF * 8) + (f0 << 3) + c4);
                float  sc = Wc[(size_t)(col0 + rr) * NF + f0 + (c4 >> 3)];
                st_bf16x4(Bs, rr, c4, sv.x * sc, sv.y * sc, sv.z * sc, sv.w * sc);
            }
            {
                const int rr = t >> 1, fh = (t & 1) << 2;
                float4 xv = *(const float4*)(X + (size_t)(row0 + rr) * NF + f0 + fh);
                float xs[4] = {xv.x, xv.y, xv.z, xv.w};
                #pragma unroll
                for (int ff = 0; ff < 4; ++ff) {
                    uint4 v = spline_pack8(xs[ff]);
                    const int cc   = (fh + ff) << 3;
                    const int byte = rr * 128 + (((cc << 1) ^ ((rr & 7) << 4)));
                    *reinterpret_cast<uint4*>(As + byte) = v;
                }
            }
        }
        __syncthreads();
        #pragma unroll
        for (int ks = 0; ks < 2; ++ks) {
            const int kc = (ks << 5) + ((lane >> 4) << 3);
            s16x8 af[4], bfr[4];
            #pragma unroll
            for (int i = 0; i < 4; ++i) {
                af[i]  = ld_frag(As, (wr  << 6) + (i << 4) + (lane & 15), kc);
                bfr[i] = ld_frag(Bs, (wcn << 6) + (i << 4) + (lane & 15), kc);
            }
            #pragma unroll
            for (int i = 0; i < 4; ++i)
                #pragma unroll
                for (int j = 0; j < 4; ++j)
                    acc[i][j] = __builtin_amdgcn_mfma_f32_16x16x32_bf16(af[i], bfr[j], acc[i][j], 0, 0, 0);
        }
    }
    const int crow = (lane >> 4) << 2, ccol = lane & 15;
    #pragma unroll
    for (int i = 0; i < 4; ++i)
        #pragma unroll
        for (int j = 0; j < 4; ++j)
            #pragma unroll
            for (int q = 0; q < 4; ++q) {
                int r = row0 + (wr << 6) + (i << 4) + crow + q;
                int c = col0 + (wcn << 6) + (j << 4) + ccol;
                float v = acc[i][j][q];
                if (ACT) v = (v >= 0.f) ? v : 0.1f * v;
                Out[(size_t)r * OF + c] = v;
            }
}

// ===========================================================================

extern "C" void kernel_launch(void* const* d_in, const int* in_sizes, int n_in,
                              void* d_out, int out_size, void* d_ws, size_t ws_size,
                              hipStream_t stream)
{
    const float* x   = (const float*)d_in[0];
    const float* w1b = (const float*)d_in[1];
    const float* w1s = (const float*)d_in[2];
    const float* w1c = (const float*)d_in[3];
    const float* w2b = (const float*)d_in[4];
    const float* w2s = (const float*)d_in[5];
    const float* w2c = (const float*)d_in[6];
    const float* w3b = (const float*)d_in[7];
    const float* w3s = (const float*)d_in[8];
    const float* w3c = (const float*)d_in[9];
    const float* w4b = (const float*)d_in[10];
    const float* w4s = (const float*)d_in[11];
    const float* w4c = (const float*)d_in[12];

    float* out    = (float*)d_out;
    float* x_dec  = out;               // (64,64,1024)
    float* x_emb  = out + 4194304;     // (64,64,1024)
    float* x_de   = out + 8388608;     // (64,64,1024)
    float* x_comb = out + 12582912;    // (64,1024)

    const size_t A_SZ = 75497472ull;       // 4096*9216*2
    const size_t B_SZ = 18874368ull;       // 1024*9216*2
    if (ws_size >= A_SZ + 2 * B_SZ) {
        const bool two_a = (ws_size >= 2 * A_SZ + 2 * B_SZ);
        char* p = (char*)d_ws;
        ushort_t* Aa  = (ushort_t*)p;                       p += A_SZ;
        ushort_t* Aa2 = Aa;
        if (two_a) { Aa2 = (ushort_t*)p;                    p += A_SZ; }
        ushort_t* B1  = (ushort_t*)p;                       p += B_SZ;
        ushort_t* B4  = (ushort_t*)p;

        prep_b<<<4608, 256, 0, stream>>>(w1b, w1s, w1c, B1);
        prep_b<<<4608, 256, 0, stream>>>(w4b, w4s, w4c, B4);
        prep_a<<<18432, 256, 0, stream>>>(x, Aa);
        kan_gemm3<1><<<512, 256, 0, stream>>>(Aa, B1, x_emb);
        kan_mid2<<<1024, 256, 0, stream>>>(x_emb, w2b, w2s, w2c, w3b, w3s, w3c, x_comb, x_de);
        prep_a<<<18432, 256, 0, stream>>>(x_de, Aa2);
        kan_gemm3<0><<<512, 256, 0, stream>>>(Aa2, B4, x_dec);
    } else {
        dim3 gg(32, 8);
        kan_gemm<1><<<gg, 256, 0, stream>>>(x, w1b, w1s, w1c, x_emb);
        // layers 2+3 via mid2 grid layout
        kan_mid2<<<1024, 256, 0, stream>>>(x_emb, w2b, w2s, w2c, w3b, w3s, w3c, x_comb, x_de);
        kan_gemm<0><<<gg, 256, 0, stream>>>(x_de, w4b, w4s, w4c, x_dec);
    }
}

// Round 4
// 1101.088 us; speedup vs baseline: 1.1280x; 1.1280x over previous
//
#include <hip/hip_runtime.h>
#include <hip/hip_bf16.h>

typedef float f32x4 __attribute__((ext_vector_type(4)));
typedef short s16x8 __attribute__((ext_vector_type(8)));
typedef unsigned int u32;
typedef unsigned short ushort_t;

#define NF 1024
#define OF 1024
#define KV 9216          // 1024 base + 1024*8 spline

static __device__ __forceinline__ float silu_f(float x) {
    return x / (1.f + __expf(-x));
}

static __device__ __forceinline__ unsigned short f2bf(float f) {
    unsigned int u = __float_as_uint(f);
    return (unsigned short)((u + 0x7FFFu + ((u >> 16) & 1u)) >> 16);
}

// Cubic B-spline over knots t_j = -2.2 + 0.4*j (j=0..11): 4 taps at slots p..p+3.
static __device__ __forceinline__ void basis_taps(float x, float w[4], int &p) {
    float t  = __fmaf_rn(x, 2.5f, 5.5f);
    float jf = floorf(t);
    float u  = t - jf;
    int   j  = (int)jf;
    float um  = 1.f - u;
    float um2 = um * um;
    float u2  = u * u;
    float w0 = um2 * um * (1.f / 6.f);
    float w3 = u2 * u * (1.f / 6.f);
    float w1 = __fmaf_rn(0.5f * u, u2, -u2) + (2.f / 3.f);
    float w2 = 1.f - w0 - w1 - w3;
    w[0] = w0; w[1] = w1; w[2] = w2; w[3] = w3;
    p = (j >= 0 && j <= 10) ? (j - 3) : -10000;
}

// 8 bf16 basis slots for one x, packed in a uint4 (taps shifted into place).
static __device__ __forceinline__ uint4 spline_pack8(float x) {
    float w[4]; int p;
    basis_taps(x, w, p);
    unsigned long long taps =
          (unsigned long long)f2bf(w[0])
        | ((unsigned long long)f2bf(w[1]) << 16)
        | ((unsigned long long)f2bf(w[2]) << 32)
        | ((unsigned long long)f2bf(w[3]) << 48);
    int bsh = p << 4;
    unsigned long long lo = 0ull, hi = 0ull;
    if (bsh >= 0) {
        if (bsh < 64)       { lo = taps << bsh; hi = bsh ? (taps >> (64 - bsh)) : 0ull; }
        else if (bsh < 128) { hi = taps << (bsh - 64); }
    } else if (bsh > -64)   { lo = taps >> (-bsh); }
    uint4 v;
    v.x = (u32)lo; v.y = (u32)(lo >> 32); v.z = (u32)hi; v.w = (u32)(hi >> 32);
    return v;
}

static __device__ __forceinline__ u32 pack2(float a, float b) {
    return (u32)f2bf(a) | ((u32)f2bf(b) << 16);
}

// ============================ FAST PATH ====================================

// A_aug (4096,9216) bf16: [0,1024) = silu(x); [1024+f*8+s] = basis_s(x_f).
__global__ __launch_bounds__(256)
void prep_a(const float* __restrict__ X, ushort_t* __restrict__ Aa) {
    const int gid = blockIdx.x * 256 + threadIdx.x;   // 4718592 threads
    if (gid < 524288) {                               // base region, 8 elems each
        const int m = gid >> 7, c8 = (gid & 127) << 3;
        const float4* xp = (const float4*)(X + (((size_t)m) << 10) + c8);
        float4 a = xp[0], b = xp[1];
        uint4 v;
        v.x = pack2(silu_f(a.x), silu_f(a.y));
        v.y = pack2(silu_f(a.z), silu_f(a.w));
        v.z = pack2(silu_f(b.x), silu_f(b.y));
        v.w = pack2(silu_f(b.z), silu_f(b.w));
        *(uint4*)(Aa + (size_t)m * KV + c8) = v;
    } else {                                          // spline region, 1 feature each
        const int sid = gid - 524288;
        const int m = sid >> 10, f = sid & 1023;
        float x = X[(((size_t)m) << 10) + f];
        *(uint4*)(Aa + (size_t)m * KV + 1024 + (f << 3)) = spline_pack8(x);
    }
}

// B_aug (1024,9216) bf16: [0,1024)=Wb; [1024+f*8+s]=Ws[o][f][s]*Wc[o][f].
__global__ __launch_bounds__(256)
void prep_b(const float* __restrict__ Wb, const float* __restrict__ Ws,
            const float* __restrict__ Wc, ushort_t* __restrict__ Ba) {
    const int gid = blockIdx.x * 256 + threadIdx.x;   // 1179648 threads
    const int o = gid / 1152;
    const int r = gid - o * 1152;
    uint4 v;
    size_t dst;
    if (r < 128) {
        const int k8 = r << 3;
        const float4* wp = (const float4*)(Wb + (((size_t)o) << 10) + k8);
        float4 a = wp[0], b = wp[1];
        v.x = pack2(a.x, a.y); v.y = pack2(a.z, a.w);
        v.z = pack2(b.x, b.y); v.w = pack2(b.z, b.w);
        dst = (size_t)o * KV + k8;
    } else {
        const int f = r - 128;
        const float sc = Wc[(((size_t)o) << 10) + f];
        const float4* sp = (const float4*)(Ws + ((((size_t)o) << 10) + f) * 8);
        float4 a = sp[0], b = sp[1];
        v.x = pack2(a.x * sc, a.y * sc); v.y = pack2(a.z * sc, a.w * sc);
        v.z = pack2(b.x * sc, b.y * sc); v.w = pack2(b.z * sc, b.w * sc);
        dst = (size_t)o * KV + 1024 + (f << 3);
    }
    *(uint4*)(Ba + dst) = v;
}

// Pure bf16 NT-GEMM: 128x64 tile, BK=64, reg-staged LDS with XOR swizzle.
// __launch_bounds__(256, 2): 2 waves/EU -> VGPR cap 256, room for acc +
// prefetch regs with NO SPILL (R3's VGPR=48 + 150MB scratch writeback bug).
template<int ACT>
__global__ __launch_bounds__(256, 2)
void kan_gemm3(const ushort_t* __restrict__ A,   // (4096, KV)
               const ushort_t* __restrict__ B,   // (1024, KV)
               float* __restrict__ Out)          // (4096, 1024)
{
    __shared__ alignas(16) char As[128 * 128];   // 128 rows x 64 bf16 (swizzled)
    __shared__ alignas(16) char Bs[64 * 128];    // 64 rows x 64 bf16 (swizzled)

    const int t = threadIdx.x, lane = t & 63, wid = t >> 6;
    const int wr = wid >> 1, wcn = wid & 1;      // 2x2 wave grid, 64x32 per wave
    // bijective XCD swizzle (512 % 8 == 0)
    const int bb  = blockIdx.x;
    const int lb  = (bb & 7) * 64 + (bb >> 3);
    const int row0 = (lb >> 4) << 7;             // 32 row-blocks
    const int col0 = (lb & 15) << 6;             // 16 col-blocks
    const int l8 = lane >> 3, l7 = lane & 7;

    f32x4 acc[4][2];
    #pragma unroll
    for (int i = 0; i < 4; ++i)
        #pragma unroll
        for (int j = 0; j < 2; ++j)
            acc[i][j] = (f32x4){0.f, 0.f, 0.f, 0.f};

    // per-thread staging map: A rows slotA*8+l8 (slotA=wid*4+i), B rows slotB*8+l8
    uint4 ra[4], rb[2];
    #pragma unroll
    for (int i = 0; i < 4; ++i) {
        const int row = (((wid << 2) + i) << 3) + l8;
        ra[i] = *(const uint4*)(A + (size_t)(row0 + row) * KV + (l7 << 3));
    }
    #pragma unroll
    for (int i = 0; i < 2; ++i) {
        const int row = (((i << 2) + wid) << 3) + l8;
        rb[i] = *(const uint4*)(B + (size_t)(col0 + row) * KV + (l7 << 3));
    }

    for (int ch = 0; ch < 144; ++ch) {
        __syncthreads();                 // prior chunk's ds_reads all done
        #pragma unroll
        for (int i = 0; i < 4; ++i) {
            const int row = (((wid << 2) + i) << 3) + l8;
            *(uint4*)(As + row * 128 + ((l7 << 4) ^ ((row & 7) << 4))) = ra[i];
        }
        #pragma unroll
        for (int i = 0; i < 2; ++i) {
            const int row = (((i << 2) + wid) << 3) + l8;
            *(uint4*)(Bs + row * 128 + ((l7 << 4) ^ ((row & 7) << 4))) = rb[i];
        }
        if (ch < 143) {                  // prefetch next chunk into regs
            const int k0 = (ch + 1) << 6;
            #pragma unroll
            for (int i = 0; i < 4; ++i) {
                const int row = (((wid << 2) + i) << 3) + l8;
                ra[i] = *(const uint4*)(A + (size_t)(row0 + row) * KV + k0 + (l7 << 3));
            }
            #pragma unroll
            for (int i = 0; i < 2; ++i) {
                const int row = (((i << 2) + wid) << 3) + l8;
                rb[i] = *(const uint4*)(B + (size_t)(col0 + row) * KV + k0 + (l7 << 3));
            }
        }
        __syncthreads();                 // ds_writes visible to all

        #pragma unroll
        for (int ks = 0; ks < 2; ++ks) {
            const int kcb = ((ks << 5) + ((lane >> 4) << 3)) << 1;   // byte offset
            s16x8 af[4], bf2[2];
            #pragma unroll
            for (int i = 0; i < 4; ++i) {
                const int r = (wr << 6) + (i << 4) + (lane & 15);
                af[i] = *(const s16x8*)(As + r * 128 + (kcb ^ ((r & 7) << 4)));
            }
            #pragma unroll
            for (int j = 0; j < 2; ++j) {
                const int r = (wcn << 5) + (j << 4) + (lane & 15);
                bf2[j] = *(const s16x8*)(Bs + r * 128 + (kcb ^ ((r & 7) << 4)));
            }
            #pragma unroll
            for (int i = 0; i < 4; ++i)
                #pragma unroll
                for (int j = 0; j < 2; ++j)
                    acc[i][j] = __builtin_amdgcn_mfma_f32_16x16x32_bf16(af[i], bf2[j], acc[i][j], 0, 0, 0);
        }
    }

    const int crow = (lane >> 4) << 2, ccol = lane & 15;
    #pragma unroll
    for (int i = 0; i < 4; ++i)
        #pragma unroll
        for (int j = 0; j < 2; ++j)
            #pragma unroll
            for (int q = 0; q < 4; ++q) {
                int r = row0 + (wr << 6) + (i << 4) + crow + q;
                int c = col0 + (wcn << 5) + (j << 4) + ccol;
                float v = acc[i][j][q];
                if (ACT) v = (v >= 0.f) ? v : 0.1f * v;
                Out[(size_t)r * OF + c] = v;
            }
}

// Fused layers 2+3, 4 wave-groups over H + LDS combine: grid 64*16 blocks.
__global__ __launch_bounds__(256)
void kan_mid2(const float* __restrict__ xemb,
              const float* __restrict__ w2b, const float* __restrict__ w2s, const float* __restrict__ w2c,
              const float* __restrict__ w3b, const float* __restrict__ w3s, const float* __restrict__ w3c,
              float* __restrict__ xcomb, float* __restrict__ xde)
{
    __shared__ float s_w2sc[64][8];
    __shared__ float s_w2b[64];
    __shared__ float s_w3sc[64][8];
    __shared__ float s_w3b[64];
    __shared__ float partial[4][64];
    __shared__ float s_acc[64];
    const int t = threadIdx.x;
    if (t < 64) { s_w2b[t] = w2b[t]; s_w3b[t] = w3b[t]; }
    for (int i = t; i < 512; i += 256) {
        s_w2sc[i >> 3][i & 7] = w2s[i] * w2c[i >> 3];
        s_w3sc[i >> 3][i & 7] = w3s[i] * w3c[i >> 3];
    }
    __syncthreads();

    const int b  = blockIdx.x >> 4;
    const int d0 = (blockIdx.x & 15) << 6;
    const int hg = t >> 6, dd = t & 63;

    float sum = 0.f;
    #pragma unroll 4
    for (int hh = 0; hh < 16; ++hh) {
        const int h = (hg << 4) + hh;
        float e = xemb[(((size_t)(b << 6) + h) << 10) + d0 + dd];
        float w[4]; int p;
        basis_taps(e, w, p);
        float sp = 0.f;
        #pragma unroll
        for (int m2 = 0; m2 < 4; ++m2) {
            int idx = p + m2;
            if ((unsigned)idx < 8u) sp += w[m2] * s_w2sc[h][idx];
        }
        sum += silu_f(e) * s_w2b[h] + sp;
    }
    partial[hg][dd] = sum;
    __syncthreads();
    if (hg == 0) {
        float a = partial[0][dd] + partial[1][dd] + partial[2][dd] + partial[3][dd];
        s_acc[dd] = a;
        xcomb[(b << 10) + d0 + dd] = a;
    }
    __syncthreads();

    const float accv = s_acc[dd];
    float w[4]; int p;
    basis_taps(accv, w, p);
    const float sl = silu_f(accv);
    #pragma unroll 4
    for (int hh = 0; hh < 16; ++hh) {
        const int h = (hg << 4) + hh;
        float sp = 0.f;
        #pragma unroll
        for (int m2 = 0; m2 < 4; ++m2) {
            int idx = p + m2;
            if ((unsigned)idx < 8u) sp += w[m2] * s_w3sc[h][idx];
        }
        float v = sl * s_w3b[h] + sp;
        v = (v >= 0.f) ? v : 0.1f * v;
        xde[(((size_t)(b << 6) + h) << 10) + d0 + dd] = v;
    }
}

// ========================= FALLBACK PATH (R1, passing) =====================

static __device__ __forceinline__ void st_bf16x4(char* lds, int r, int c4,
                                                 float a, float b, float c, float d) {
    unsigned int lo = (unsigned int)f2bf(a) | ((unsigned int)f2bf(b) << 16);
    unsigned int hi = (unsigned int)f2bf(c) | ((unsigned int)f2bf(d) << 16);
    int byte = r * 128 + (((c4 << 1) ^ ((r & 7) << 4)));
    uint2 v; v.x = lo; v.y = hi;
    *reinterpret_cast<uint2*>(lds + byte) = v;
}

static __device__ __forceinline__ s16x8 ld_frag(const char* lds, int r, int c) {
    int byte = r * 128 + (((c << 1) ^ ((r & 7) << 4)));
    return *reinterpret_cast<const s16x8*>(lds + byte);
}

template<int ACT>
__global__ __launch_bounds__(256)
void kan_gemm(const float* __restrict__ X, const float* __restrict__ Wb,
              const float* __restrict__ Ws, const float* __restrict__ Wc,
              float* __restrict__ Out)
{
    __shared__ alignas(16) char As[128 * 128];
    __shared__ alignas(16) char Bs[128 * 128];
    const int t = threadIdx.x, lane = t & 63, wid = t >> 6;
    const int wr = wid >> 1, wcn = wid & 1;
    const int row0 = blockIdx.x * 128, col0 = blockIdx.y * 128;
    f32x4 acc[4][4];
    #pragma unroll
    for (int i = 0; i < 4; ++i)
        #pragma unroll
        for (int j = 0; j < 4; ++j) acc[i][j] = (f32x4){0.f, 0.f, 0.f, 0.f};
    const int rs = t >> 4, c4 = (t & 15) << 2;
    for (int ch = 0; ch < 144; ++ch) {
        __syncthreads();
        if (ch < 16) {
            const int i0 = ch << 6;
            #pragma unroll
            for (int ps = 0; ps < 8; ++ps) {
                const int rr = (ps << 4) + rs;
                float4 xv = *(const float4*)(X + (size_t)(row0 + rr) * NF + i0 + c4);
                st_bf16x4(As, rr, c4, silu_f(xv.x), silu_f(xv.y), silu_f(xv.z), silu_f(xv.w));
                float4 wv = *(const float4*)(Wb + (size_t)(col0 + rr) * NF + i0 + c4);
                st_bf16x4(Bs, rr, c4, wv.x, wv.y, wv.z, wv.w);
            }
        } else {
            const int f0 = (ch - 16) << 3;
            #pragma unroll
            for (int ps = 0; ps < 8; ++ps) {
                const int rr = (ps << 4) + rs;
                float4 sv = *(const float4*)(Ws + (size_t)(col0 + rr) * (NF * 8) + (f0 << 3) + c4);
                float  sc = Wc[(size_t)(col0 + rr) * NF + f0 + (c4 >> 3)];
                st_bf16x4(Bs, rr, c4, sv.x * sc, sv.y * sc, sv.z * sc, sv.w * sc);
            }
            {
                const int rr = t >> 1, fh = (t & 1) << 2;
                float4 xv = *(const float4*)(X + (size_t)(row0 + rr) * NF + f0 + fh);
                float xs[4] = {xv.x, xv.y, xv.z, xv.w};
                #pragma unroll
                for (int ff = 0; ff < 4; ++ff) {
                    uint4 v = spline_pack8(xs[ff]);
                    const int cc   = (fh + ff) << 3;
                    const int byte = rr * 128 + (((cc << 1) ^ ((rr & 7) << 4)));
                    *reinterpret_cast<uint4*>(As + byte) = v;
                }
            }
        }
        __syncthreads();
        #pragma unroll
        for (int ks = 0; ks < 2; ++ks) {
            const int kc = (ks << 5) + ((lane >> 4) << 3);
            s16x8 af[4], bfr[4];
            #pragma unroll
            for (int i = 0; i < 4; ++i) {
                af[i]  = ld_frag(As, (wr  << 6) + (i << 4) + (lane & 15), kc);
                bfr[i] = ld_frag(Bs, (wcn << 6) + (i << 4) + (lane & 15), kc);
            }
            #pragma unroll
            for (int i = 0; i < 4; ++i)
                #pragma unroll
                for (int j = 0; j < 4; ++j)
                    acc[i][j] = __builtin_amdgcn_mfma_f32_16x16x32_bf16(af[i], bfr[j], acc[i][j], 0, 0, 0);
        }
    }
    const int crow = (lane >> 4) << 2, ccol = lane & 15;
    #pragma unroll
    for (int i = 0; i < 4; ++i)
        #pragma unroll
        for (int j = 0; j < 4; ++j)
            #pragma unroll
            for (int q = 0; q < 4; ++q) {
                int r = row0 + (wr << 6) + (i << 4) + crow + q;
                int c = col0 + (wcn << 6) + (j << 4) + ccol;
                float v = acc[i][j][q];
                if (ACT) v = (v >= 0.f) ? v : 0.1f * v;
                Out[(size_t)r * OF + c] = v;
            }
}

// ===========================================================================

extern "C" void kernel_launch(void* const* d_in, const int* in_sizes, int n_in,
                              void* d_out, int out_size, void* d_ws, size_t ws_size,
                              hipStream_t stream)
{
    const float* x   = (const float*)d_in[0];
    const float* w1b = (const float*)d_in[1];
    const float* w1s = (const float*)d_in[2];
    const float* w1c = (const float*)d_in[3];
    const float* w2b = (const float*)d_in[4];
    const float* w2s = (const float*)d_in[5];
    const float* w2c = (const float*)d_in[6];
    const float* w3b = (const float*)d_in[7];
    const float* w3s = (const float*)d_in[8];
    const float* w3c = (const float*)d_in[9];
    const float* w4b = (const float*)d_in[10];
    const float* w4s = (const float*)d_in[11];
    const float* w4c = (const float*)d_in[12];

    float* out    = (float*)d_out;
    float* x_dec  = out;               // (64,64,1024)
    float* x_emb  = out + 4194304;     // (64,64,1024)
    float* x_de   = out + 8388608;     // (64,64,1024)
    float* x_comb = out + 12582912;    // (64,1024)

    const size_t A_SZ = 75497472ull;       // 4096*9216*2
    const size_t B_SZ = 18874368ull;       // 1024*9216*2
    if (ws_size >= A_SZ + 2 * B_SZ) {
        const bool two_a = (ws_size >= 2 * A_SZ + 2 * B_SZ);
        char* p = (char*)d_ws;
        ushort_t* Aa  = (ushort_t*)p;                       p += A_SZ;
        ushort_t* Aa2 = Aa;
        if (two_a) { Aa2 = (ushort_t*)p;                    p += A_SZ; }
        ushort_t* B1  = (ushort_t*)p;                       p += B_SZ;
        ushort_t* B4  = (ushort_t*)p;

        prep_b<<<4608, 256, 0, stream>>>(w1b, w1s, w1c, B1);
        prep_b<<<4608, 256, 0, stream>>>(w4b, w4s, w4c, B4);
        prep_a<<<18432, 256, 0, stream>>>(x, Aa);
        kan_gemm3<1><<<512, 256, 0, stream>>>(Aa, B1, x_emb);
        kan_mid2<<<1024, 256, 0, stream>>>(x_emb, w2b, w2s, w2c, w3b, w3s, w3c, x_comb, x_de);
        prep_a<<<18432, 256, 0, stream>>>(x_de, Aa2);
        kan_gemm3<0><<<512, 256, 0, stream>>>(Aa2, B4, x_dec);
    } else {
        dim3 gg(32, 8);
        kan_gemm<1><<<gg, 256, 0, stream>>>(x, w1b, w1s, w1c, x_emb);
        kan_mid2<<<1024, 256, 0, stream>>>(x_emb, w2b, w2s, w2c, w3b, w3s, w3c, x_comb, x_de);
        kan_gemm<0><<<gg, 256, 0, stream>>>(x_de, w4b, w4s, w4c, x_dec);
    }
}

// Round 5
// 423.763 us; speedup vs baseline: 2.9310x; 2.5984x over previous
//
#include <hip/hip_runtime.h>
#include <hip/hip_bf16.h>

typedef float f32x4 __attribute__((ext_vector_type(4)));
typedef short s16x8 __attribute__((ext_vector_type(8)));
typedef unsigned int u32;
typedef unsigned short ushort_t;

#define NF 1024
#define OF 1024
#define KV 9216          // 1024 base + 1024*8 spline

static __device__ __forceinline__ float silu_f(float x) {
    return x / (1.f + __expf(-x));
}

static __device__ __forceinline__ unsigned short f2bf(float f) {
    unsigned int u = __float_as_uint(f);
    return (unsigned short)((u + 0x7FFFu + ((u >> 16) & 1u)) >> 16);
}

// Cubic B-spline over knots t_j = -2.2 + 0.4*j (j=0..11): 4 taps at slots p..p+3.
static __device__ __forceinline__ void basis_taps(float x, float w[4], int &p) {
    float t  = __fmaf_rn(x, 2.5f, 5.5f);
    float jf = floorf(t);
    float u  = t - jf;
    int   j  = (int)jf;
    float um  = 1.f - u;
    float um2 = um * um;
    float u2  = u * u;
    float w0 = um2 * um * (1.f / 6.f);
    float w3 = u2 * u * (1.f / 6.f);
    float w1 = __fmaf_rn(0.5f * u, u2, -u2) + (2.f / 3.f);
    float w2 = 1.f - w0 - w1 - w3;
    w[0] = w0; w[1] = w1; w[2] = w2; w[3] = w3;
    p = (j >= 0 && j <= 10) ? (j - 3) : -10000;
}

// 8 bf16 basis slots for one x, packed in a uint4 (taps shifted into place).
static __device__ __forceinline__ uint4 spline_pack8(float x) {
    float w[4]; int p;
    basis_taps(x, w, p);
    unsigned long long taps =
          (unsigned long long)f2bf(w[0])
        | ((unsigned long long)f2bf(w[1]) << 16)
        | ((unsigned long long)f2bf(w[2]) << 32)
        | ((unsigned long long)f2bf(w[3]) << 48);
    int bsh = p << 4;
    unsigned long long lo = 0ull, hi = 0ull;
    if (bsh >= 0) {
        if (bsh < 64)       { lo = taps << bsh; hi = bsh ? (taps >> (64 - bsh)) : 0ull; }
        else if (bsh < 128) { hi = taps << (bsh - 64); }
    } else if (bsh > -64)   { lo = taps >> (-bsh); }
    uint4 v;
    v.x = (u32)lo; v.y = (u32)(lo >> 32); v.z = (u32)hi; v.w = (u32)(hi >> 32);
    return v;
}

static __device__ __forceinline__ u32 pack2(float a, float b) {
    return (u32)f2bf(a) | ((u32)f2bf(b) << 16);
}

// ============================ FAST PATH ====================================

// A_aug (4096,9216) bf16: [0,1024) = silu(x); [1024+f*8+s] = basis_s(x_f).
__global__ __launch_bounds__(256)
void prep_a(const float* __restrict__ X, ushort_t* __restrict__ Aa) {
    const int gid = blockIdx.x * 256 + threadIdx.x;   // 4718592 threads
    if (gid < 524288) {                               // base region, 8 elems each
        const int m = gid >> 7, c8 = (gid & 127) << 3;
        const float4* xp = (const float4*)(X + (((size_t)m) << 10) + c8);
        float4 a = xp[0], b = xp[1];
        uint4 v;
        v.x = pack2(silu_f(a.x), silu_f(a.y));
        v.y = pack2(silu_f(a.z), silu_f(a.w));
        v.z = pack2(silu_f(b.x), silu_f(b.y));
        v.w = pack2(silu_f(b.z), silu_f(b.w));
        *(uint4*)(Aa + (size_t)m * KV + c8) = v;
    } else {                                          // spline region, 1 feature each
        const int sid = gid - 524288;
        const int m = sid >> 10, f = sid & 1023;
        float x = X[(((size_t)m) << 10) + f];
        *(uint4*)(Aa + (size_t)m * KV + 1024 + (f << 3)) = spline_pack8(x);
    }
}

// B_aug (1024,9216) bf16: [0,1024)=Wb; [1024+f*8+s]=Ws[o][f][s]*Wc[o][f].
__global__ __launch_bounds__(256)
void prep_b(const float* __restrict__ Wb, const float* __restrict__ Ws,
            const float* __restrict__ Wc, ushort_t* __restrict__ Ba) {
    const int gid = blockIdx.x * 256 + threadIdx.x;   // 1179648 threads
    const int o = gid / 1152;
    const int r = gid - o * 1152;
    uint4 v;
    size_t dst;
    if (r < 128) {
        const int k8 = r << 3;
        const float4* wp = (const float4*)(Wb + (((size_t)o) << 10) + k8);
        float4 a = wp[0], b = wp[1];
        v.x = pack2(a.x, a.y); v.y = pack2(a.z, a.w);
        v.z = pack2(b.x, b.y); v.w = pack2(b.z, b.w);
        dst = (size_t)o * KV + k8;
    } else {
        const int f = r - 128;
        const float sc = Wc[(((size_t)o) << 10) + f];
        const float4* sp = (const float4*)(Ws + ((((size_t)o) << 10) + f) * 8);
        float4 a = sp[0], b = sp[1];
        v.x = pack2(a.x * sc, a.y * sc); v.y = pack2(a.z * sc, a.w * sc);
        v.z = pack2(b.x * sc, b.y * sc); v.w = pack2(b.z * sc, b.w * sc);
        dst = (size_t)o * KV + 1024 + (f << 3);
    }
    *(uint4*)(Ba + dst) = v;
}

// Pure bf16 NT-GEMM: 128x64 tile, BK=64, LDS double-buffer (state in LDS,
// NOT loop-carried VGPR arrays — R3/R4's scratch-demotion bug). Per chunk:
// issue next loads (named temps) -> compute current buf -> write temps ->
// one barrier. Buffer parity is compile-time (manual 2x unroll + peel).
template<int ACT>
__global__ __launch_bounds__(256)
void kan_gemm5(const ushort_t* __restrict__ A,   // (4096, KV)
               const ushort_t* __restrict__ B,   // (1024, KV)
               float* __restrict__ Out)          // (4096, 1024)
{
    __shared__ alignas(16) char As[2][128 * 128];   // 128 rows x 64 bf16, swizzled
    __shared__ alignas(16) char Bs[2][64 * 128];    // 64 rows x 64 bf16, swizzled

    const int t = threadIdx.x, lane = t & 63, wid = t >> 6;
    const int wr = wid >> 1, wcn = wid & 1;      // 2x2 wave grid, 64x32 per wave
    // bijective XCD swizzle (512 % 8 == 0)
    const int bb  = blockIdx.x;
    const int lb  = (bb & 7) * 64 + (bb >> 3);
    const int row0 = (lb >> 4) << 7;             // 32 row-blocks
    const int col0 = (lb & 15) << 6;             // 16 col-blocks
    const int l8 = lane >> 3, l7 = lane & 7;

    // staging rows (static per thread): A rows (wid*4+i)*8+l8, B rows (i*4+wid)*8+l8
    const int rA0 = (((wid << 2) + 0) << 3) + l8;
    const int rA1 = (((wid << 2) + 1) << 3) + l8;
    const int rA2 = (((wid << 2) + 2) << 3) + l8;
    const int rA3 = (((wid << 2) + 3) << 3) + l8;
    const int rB0 = ((wid) << 3) + l8;
    const int rB1 = (((4 + wid)) << 3) + l8;

    const ushort_t* pa0 = A + (size_t)(row0 + rA0) * KV + (l7 << 3);
    const ushort_t* pa1 = A + (size_t)(row0 + rA1) * KV + (l7 << 3);
    const ushort_t* pa2 = A + (size_t)(row0 + rA2) * KV + (l7 << 3);
    const ushort_t* pa3 = A + (size_t)(row0 + rA3) * KV + (l7 << 3);
    const ushort_t* pb0 = B + (size_t)(col0 + rB0) * KV + (l7 << 3);
    const ushort_t* pb1 = B + (size_t)(col0 + rB1) * KV + (l7 << 3);

    // LDS write byte offsets: row*128 + ((l7^ (row&7))<<4); row&7 == l8 here.
    const int swz = ((l7 ^ l8) << 4);
    const int wA0 = rA0 * 128 + swz;
    const int wA1 = rA1 * 128 + swz;
    const int wA2 = rA2 * 128 + swz;
    const int wA3 = rA3 * 128 + swz;
    const int wB0 = rB0 * 128 + swz;
    const int wB1 = rB1 * 128 + swz;

    f32x4 acc[4][2];
    #pragma unroll
    for (int i = 0; i < 4; ++i)
        #pragma unroll
        for (int j = 0; j < 2; ++j)
            acc[i][j] = (f32x4){0.f, 0.f, 0.f, 0.f};

    uint4 ta0, ta1, ta2, ta3, tb0, tb1;

#define LOADT(CH) {                                   \
    const size_t o_ = (size_t)(CH) << 6;              \
    ta0 = *(const uint4*)(pa0 + o_);                  \
    ta1 = *(const uint4*)(pa1 + o_);                  \
    ta2 = *(const uint4*)(pa2 + o_);                  \
    ta3 = *(const uint4*)(pa3 + o_);                  \
    tb0 = *(const uint4*)(pb0 + o_);                  \
    tb1 = *(const uint4*)(pb1 + o_);                  \
}

#define WRITET(BUF) {                                 \
    *(uint4*)(As[BUF] + wA0) = ta0;                   \
    *(uint4*)(As[BUF] + wA1) = ta1;                   \
    *(uint4*)(As[BUF] + wA2) = ta2;                   \
    *(uint4*)(As[BUF] + wA3) = ta3;                   \
    *(uint4*)(Bs[BUF] + wB0) = tb0;                   \
    *(uint4*)(Bs[BUF] + wB1) = tb1;                   \
}

#define COMPUTE(BUF) {                                                         \
    _Pragma("unroll")                                                          \
    for (int ks = 0; ks < 2; ++ks) {                                           \
        const int kcb = ((ks << 5) + ((lane >> 4) << 3)) << 1;                 \
        s16x8 af[4], bf2[2];                                                   \
        _Pragma("unroll")                                                      \
        for (int i = 0; i < 4; ++i) {                                          \
            const int r = (wr << 6) + (i << 4) + (lane & 15);                  \
            af[i] = *(const s16x8*)(As[BUF] + r * 128 + (kcb ^ ((r & 7) << 4)));\
        }                                                                      \
        _Pragma("unroll")                                                      \
        for (int j = 0; j < 2; ++j) {                                          \
            const int r = (wcn << 5) + (j << 4) + (lane & 15);                 \
            bf2[j] = *(const s16x8*)(Bs[BUF] + r * 128 + (kcb ^ ((r & 7) << 4)));\
        }                                                                      \
        _Pragma("unroll")                                                      \
        for (int i = 0; i < 4; ++i)                                            \
            _Pragma("unroll")                                                  \
            for (int j = 0; j < 2; ++j)                                        \
                acc[i][j] = __builtin_amdgcn_mfma_f32_16x16x32_bf16(           \
                                af[i], bf2[j], acc[i][j], 0, 0, 0);            \
    }                                                                          \
}

    // prologue: stage chunk 0 into buf 0
    LOADT(0);
    WRITET(0);
    __syncthreads();

    // main: chunks 0..141 in pairs (buffer parity compile-time)
    for (int ch2 = 0; ch2 < 71; ++ch2) {
        const int c = ch2 << 1;
        LOADT(c + 1);  COMPUTE(0);  WRITET(1);  __syncthreads();
        LOADT(c + 2);  COMPUTE(1);  WRITET(0);  __syncthreads();
    }
    // ch = 142
    LOADT(143);  COMPUTE(0);  WRITET(1);  __syncthreads();
    // ch = 143
    COMPUTE(1);

#undef LOADT
#undef WRITET
#undef COMPUTE

    const int crow = (lane >> 4) << 2, ccol = lane & 15;
    #pragma unroll
    for (int i = 0; i < 4; ++i)
        #pragma unroll
        for (int j = 0; j < 2; ++j)
            #pragma unroll
            for (int q = 0; q < 4; ++q) {
                int r = row0 + (wr << 6) + (i << 4) + crow + q;
                int c = col0 + (wcn << 5) + (j << 4) + ccol;
                float v = acc[i][j][q];
                if (ACT) v = (v >= 0.f) ? v : 0.1f * v;
                Out[(size_t)r * OF + c] = v;
            }
}

// Fused layers 2+3, 4 wave-groups over H + LDS combine: grid 64*16 blocks.
__global__ __launch_bounds__(256)
void kan_mid2(const float* __restrict__ xemb,
              const float* __restrict__ w2b, const float* __restrict__ w2s, const float* __restrict__ w2c,
              const float* __restrict__ w3b, const float* __restrict__ w3s, const float* __restrict__ w3c,
              float* __restrict__ xcomb, float* __restrict__ xde)
{
    __shared__ float s_w2sc[64][8];
    __shared__ float s_w2b[64];
    __shared__ float s_w3sc[64][8];
    __shared__ float s_w3b[64];
    __shared__ float partial[4][64];
    __shared__ float s_acc[64];
    const int t = threadIdx.x;
    if (t < 64) { s_w2b[t] = w2b[t]; s_w3b[t] = w3b[t]; }
    for (int i = t; i < 512; i += 256) {
        s_w2sc[i >> 3][i & 7] = w2s[i] * w2c[i >> 3];
        s_w3sc[i >> 3][i & 7] = w3s[i] * w3c[i >> 3];
    }
    __syncthreads();

    const int b  = blockIdx.x >> 4;
    const int d0 = (blockIdx.x & 15) << 6;
    const int hg = t >> 6, dd = t & 63;

    float sum = 0.f;
    #pragma unroll 4
    for (int hh = 0; hh < 16; ++hh) {
        const int h = (hg << 4) + hh;
        float e = xemb[(((size_t)(b << 6) + h) << 10) + d0 + dd];
        float w[4]; int p;
        basis_taps(e, w, p);
        float sp = 0.f;
        #pragma unroll
        for (int m2 = 0; m2 < 4; ++m2) {
            int idx = p + m2;
            if ((unsigned)idx < 8u) sp += w[m2] * s_w2sc[h][idx];
        }
        sum += silu_f(e) * s_w2b[h] + sp;
    }
    partial[hg][dd] = sum;
    __syncthreads();
    if (hg == 0) {
        float a = partial[0][dd] + partial[1][dd] + partial[2][dd] + partial[3][dd];
        s_acc[dd] = a;
        xcomb[(b << 10) + d0 + dd] = a;
    }
    __syncthreads();

    const float accv = s_acc[dd];
    float w[4]; int p;
    basis_taps(accv, w, p);
    const float sl = silu_f(accv);
    #pragma unroll 4
    for (int hh = 0; hh < 16; ++hh) {
        const int h = (hg << 4) + hh;
        float sp = 0.f;
        #pragma unroll
        for (int m2 = 0; m2 < 4; ++m2) {
            int idx = p + m2;
            if ((unsigned)idx < 8u) sp += w[m2] * s_w3sc[h][idx];
        }
        float v = sl * s_w3b[h] + sp;
        v = (v >= 0.f) ? v : 0.1f * v;
        xde[(((size_t)(b << 6) + h) << 10) + d0 + dd] = v;
    }
}

// ========================= FALLBACK PATH (R1, passing) =====================

static __device__ __forceinline__ void st_bf16x4(char* lds, int r, int c4,
                                                 float a, float b, float c, float d) {
    unsigned int lo = (unsigned int)f2bf(a) | ((unsigned int)f2bf(b) << 16);
    unsigned int hi = (unsigned int)f2bf(c) | ((unsigned int)f2bf(d) << 16);
    int byte = r * 128 + (((c4 << 1) ^ ((r & 7) << 4)));
    uint2 v; v.x = lo; v.y = hi;
    *reinterpret_cast<uint2*>(lds + byte) = v;
}

static __device__ __forceinline__ s16x8 ld_frag(const char* lds, int r, int c) {
    int byte = r * 128 + (((c << 1) ^ ((r & 7) << 4)));
    return *reinterpret_cast<const s16x8*>(lds + byte);
}

template<int ACT>
__global__ __launch_bounds__(256)
void kan_gemm(const float* __restrict__ X, const float* __restrict__ Wb,
              const float* __restrict__ Ws, const float* __restrict__ Wc,
              float* __restrict__ Out)
{
    __shared__ alignas(16) char As[128 * 128];
    __shared__ alignas(16) char Bs[128 * 128];
    const int t = threadIdx.x, lane = t & 63, wid = t >> 6;
    const int wr = wid >> 1, wcn = wid & 1;
    const int row0 = blockIdx.x * 128, col0 = blockIdx.y * 128;
    f32x4 acc[4][4];
    #pragma unroll
    for (int i = 0; i < 4; ++i)
        #pragma unroll
        for (int j = 0; j < 4; ++j) acc[i][j] = (f32x4){0.f, 0.f, 0.f, 0.f};
    const int rs = t >> 4, c4 = (t & 15) << 2;
    for (int ch = 0; ch < 144; ++ch) {
        __syncthreads();
        if (ch < 16) {
            const int i0 = ch << 6;
            #pragma unroll
            for (int ps = 0; ps < 8; ++ps) {
                const int rr = (ps << 4) + rs;
                float4 xv = *(const float4*)(X + (size_t)(row0 + rr) * NF + i0 + c4);
                st_bf16x4(As, rr, c4, silu_f(xv.x), silu_f(xv.y), silu_f(xv.z), silu_f(xv.w));
                float4 wv = *(const float4*)(Wb + (size_t)(col0 + rr) * NF + i0 + c4);
                st_bf16x4(Bs, rr, c4, wv.x, wv.y, wv.z, wv.w);
            }
        } else {
            const int f0 = (ch - 16) << 3;
            #pragma unroll
            for (int ps = 0; ps < 8; ++ps) {
                const int rr = (ps << 4) + rs;
                float4 sv = *(const float4*)(Ws + (size_t)(col0 + rr) * (NF * 8) + (f0 << 3) + c4);
                float  sc = Wc[(size_t)(col0 + rr) * NF + f0 + (c4 >> 3)];
                st_bf16x4(Bs, rr, c4, sv.x * sc, sv.y * sc, sv.z * sc, sv.w * sc);
            }
            {
                const int rr = t >> 1, fh = (t & 1) << 2;
                float4 xv = *(const float4*)(X + (size_t)(row0 + rr) * NF + f0 + fh);
                float xs[4] = {xv.x, xv.y, xv.z, xv.w};
                #pragma unroll
                for (int ff = 0; ff < 4; ++ff) {
                    uint4 v = spline_pack8(xs[ff]);
                    const int cc   = (fh + ff) << 3;
                    const int byte = rr * 128 + (((cc << 1) ^ ((rr & 7) << 4)));
                    *reinterpret_cast<uint4*>(As + byte) = v;
                }
            }
        }
        __syncthreads();
        #pragma unroll
        for (int ks = 0; ks < 2; ++ks) {
            const int kc = (ks << 5) + ((lane >> 4) << 3);
            s16x8 af[4], bfr[4];
            #pragma unroll
            for (int i = 0; i < 4; ++i) {
                af[i]  = ld_frag(As, (wr  << 6) + (i << 4) + (lane & 15), kc);
                bfr[i] = ld_frag(Bs, (wcn << 6) + (i << 4) + (lane & 15), kc);
            }
            #pragma unroll
            for (int i = 0; i < 4; ++i)
                #pragma unroll
                for (int j = 0; j < 4; ++j)
                    acc[i][j] = __builtin_amdgcn_mfma_f32_16x16x32_bf16(af[i], bfr[j], acc[i][j], 0, 0, 0);
        }
    }
    const int crow = (lane >> 4) << 2, ccol = lane & 15;
    #pragma unroll
    for (int i = 0; i < 4; ++i)
        #pragma unroll
        for (int j = 0; j < 4; ++j)
            #pragma unroll
            for (int q = 0; q < 4; ++q) {
                int r = row0 + (wr << 6) + (i << 4) + crow + q;
                int c = col0 + (wcn << 6) + (j << 4) + ccol;
                float v = acc[i][j][q];
                if (ACT) v = (v >= 0.f) ? v : 0.1f * v;
                Out[(size_t)r * OF + c] = v;
            }
}

// ===========================================================================

extern "C" void kernel_launch(void* const* d_in, const int* in_sizes, int n_in,
                              void* d_out, int out_size, void* d_ws, size_t ws_size,
                              hipStream_t stream)
{
    const float* x   = (const float*)d_in[0];
    const float* w1b = (const float*)d_in[1];
    const float* w1s = (const float*)d_in[2];
    const float* w1c = (const float*)d_in[3];
    const float* w2b = (const float*)d_in[4];
    const float* w2s = (const float*)d_in[5];
    const float* w2c = (const float*)d_in[6];
    const float* w3b = (const float*)d_in[7];
    const float* w3s = (const float*)d_in[8];
    const float* w3c = (const float*)d_in[9];
    const float* w4b = (const float*)d_in[10];
    const float* w4s = (const float*)d_in[11];
    const float* w4c = (const float*)d_in[12];

    float* out    = (float*)d_out;
    float* x_dec  = out;               // (64,64,1024)
    float* x_emb  = out + 4194304;     // (64,64,1024)
    float* x_de   = out + 8388608;     // (64,64,1024)
    float* x_comb = out + 12582912;    // (64,1024)

    const size_t A_SZ = 75497472ull;       // 4096*9216*2
    const size_t B_SZ = 18874368ull;       // 1024*9216*2
    if (ws_size >= A_SZ + 2 * B_SZ) {
        const bool two_a = (ws_size >= 2 * A_SZ + 2 * B_SZ);
        char* p = (char*)d_ws;
        ushort_t* Aa  = (ushort_t*)p;                       p += A_SZ;
        ushort_t* Aa2 = Aa;
        if (two_a) { Aa2 = (ushort_t*)p;                    p += A_SZ; }
        ushort_t* B1  = (ushort_t*)p;                       p += B_SZ;
        ushort_t* B4  = (ushort_t*)p;

        prep_b<<<4608, 256, 0, stream>>>(w1b, w1s, w1c, B1);
        prep_b<<<4608, 256, 0, stream>>>(w4b, w4s, w4c, B4);
        prep_a<<<18432, 256, 0, stream>>>(x, Aa);
        kan_gemm5<1><<<512, 256, 0, stream>>>(Aa, B1, x_emb);
        kan_mid2<<<1024, 256, 0, stream>>>(x_emb, w2b, w2s, w2c, w3b, w3s, w3c, x_comb, x_de);
        prep_a<<<18432, 256, 0, stream>>>(x_de, Aa2);
        kan_gemm5<0><<<512, 256, 0, stream>>>(Aa2, B4, x_dec);
    } else {
        dim3 gg(32, 8);
        kan_gemm<1><<<gg, 256, 0, stream>>>(x, w1b, w1s, w1c, x_emb);
        kan_mid2<<<1024, 256, 0, stream>>>(x_emb, w2b, w2s, w2c, w3b, w3s, w3c, x_comb, x_de);
        kan_gemm<0><<<gg, 256, 0, stream>>>(x_de, w4b, w4s, w4c, x_dec);
    }
}